// Round 8
// baseline (173.217 us; speedup 1.0000x reference)
//
#include <hip/hip_runtime.h>
#include <hip/hip_bf16.h>
#include <stdint.h>

// Problem constants
#define NB 2
#define NS 2048
#define ND 1024
#define NH 16
#define NDK 64
#define NM (NB*NS)   // 4096 rows

using bf16x8 = __attribute__((ext_vector_type(8))) short;   // 8 bf16 (4 VGPRs)
using f32x4  = __attribute__((ext_vector_type(4))) float;   // 4 fp32
using f32x16 = __attribute__((ext_vector_type(16))) float;  // 16 fp32
using u32x4  = __attribute__((ext_vector_type(4))) unsigned;

__device__ __forceinline__ unsigned short f2bf(float f){
  unsigned u = __float_as_uint(f);
  u += 0x7fffu + ((u>>16)&1u);          // RNE
  return (unsigned short)(u>>16);
}

__device__ __forceinline__ void gload_lds16(const void* g, void* l){
  __builtin_amdgcn_global_load_lds((const __attribute__((address_space(1))) void*)g,
                                   (__attribute__((address_space(3))) void*)l, 16, 0, 0);
}

__device__ __forceinline__ float fexp2(float x){
#if __has_builtin(__builtin_amdgcn_exp2f)
  return __builtin_amdgcn_exp2f(x);
#else
  return __expf(x * 0.69314718056f);
#endif
}

__device__ __forceinline__ unsigned cvtpk_bf16(float lo, float hi){
  unsigned r;
  asm("v_cvt_pk_bf16_f32 %0, %1, %2" : "=v"(r) : "v"(lo), "v"(hi));
  return r;
}

__device__ __forceinline__ void swap32(unsigned &a, unsigned &b){
#if __has_builtin(__builtin_amdgcn_permlane32_swap)
  auto rr = __builtin_amdgcn_permlane32_swap((int)a, (int)b, false, false);
  a = (unsigned)rr[0]; b = (unsigned)rr[1];
#else
  const bool lo = (threadIdx.x & 32) == 0;
  unsigned sa = (unsigned)__shfl_xor((int)a, 32, 64);
  unsigned sb = (unsigned)__shfl_xor((int)b, 32, 64);
  unsigned na = lo ? a : sb;
  unsigned nb = lo ? sa : b;
  a = na; b = nb;
#endif
}

__device__ __forceinline__ f32x16 mfma32(bf16x8 a, bf16x8 b, f32x16 c){
  return __builtin_amdgcn_mfma_f32_32x32x16_bf16(a, b, c, 0, 0, 0);
}

// ---------------- fused prep: all fp32->bf16 casts in ONE dispatch ----------------
__global__ __launch_bounds__(256) void prep_k(const float* __restrict__ Q, const float* __restrict__ K,
                                              const float* __restrict__ V, const float* __restrict__ Wq,
                                              const float* __restrict__ Wk, const float* __restrict__ Wv,
                                              const float* __restrict__ Wo,
                                              unsigned short* __restrict__ Xbf,
                                              unsigned short* __restrict__ Wbf){
  const int bid = blockIdx.x;
  const float* src; unsigned short* dst; int i;
  if (bid < 12288){
    const int which = bid >> 12;
    src = (which==0) ? Q : (which==1) ? K : V;
    dst = Xbf + ((size_t)which << 22);
    i = (bid & 4095)*256 + threadIdx.x;
  } else {
    const int which = (bid - 12288) >> 10;
    src = (which==0) ? Wq : (which==1) ? Wk : (which==2) ? Wv : Wo;
    dst = Wbf + ((size_t)which << 20);
    i = ((bid - 12288) & 1023)*256 + threadIdx.x;
  }
  float4 v = ((const float4*)src)[i];
  ushort4 o;
  o.x = f2bf(v.x); o.y = f2bf(v.y); o.z = f2bf(v.z); o.w = f2bf(v.w);
  ((ushort4*)dst)[i] = o;
}

// ---------------- QKV GEMM: 128x128 m97 core, 768 blocks, XCD-chunked remap ----------------
__global__ __launch_bounds__(256) void gemm_qkv(const short* __restrict__ Xbf, const short* __restrict__ Wbf,
                                                unsigned short* __restrict__ qh, unsigned short* __restrict__ kh,
                                                unsigned short* __restrict__ vT){
  __shared__ short lsA[2][4096];
  __shared__ short lsB[2][4096];
  const int tid = threadIdx.x;
  const int hw = blockIdx.x;                         // 768 blocks
  const int logical = (hw & 7)*96 + (hw >> 3);       // bijective (768 = 8*96)
  const int z = logical >> 8, rem = logical & 255;
  const int my = rem >> 3, nx = rem & 7;
  const short* A = Xbf + (size_t)z*NM*ND;
  const short* W = Wbf + (size_t)z*ND*ND;
  unsigned short* out = (z==0) ? qh : (z==1) ? kh : vT;
  const int mode = (z==2) ? 1 : 0;
  const int m0 = my*128, n0 = nx*128;

  const short* gA = A + (size_t)m0*1024;
  const short* gB = W + (size_t)n0*1024;
  const int srow = tid>>2, scol = (tid&3)*8;
  const int w = tid>>6, lane = tid&63, lr = lane&15, lk = lane>>4;
  const int wm = w>>1, wn = w&1;

  f32x4 acc[4][4];
  #pragma unroll
  for (int i=0;i<4;++i)
    #pragma unroll
    for (int j=0;j<4;++j) acc[i][j] = (f32x4){0.f,0.f,0.f,0.f};

  #pragma unroll
  for (int r=0;r<2;++r){
    gload_lds16(gA + (size_t)(r*64+srow)*1024 + scol, &lsA[0][(r*256+tid)*8]);
    gload_lds16(gB + (size_t)(r*64+srow)*1024 + scol, &lsB[0][(r*256+tid)*8]);
  }
  int cur = 0;
  for (int ks=0; ks<32; ++ks){
    __syncthreads();
    if (ks+1 < 32){
      const int k0 = (ks+1)*32;
      #pragma unroll
      for (int r=0;r<2;++r){
        gload_lds16(gA + (size_t)(r*64+srow)*1024 + k0 + scol, &lsA[cur^1][(r*256+tid)*8]);
        gload_lds16(gB + (size_t)(r*64+srow)*1024 + k0 + scol, &lsB[cur^1][(r*256+tid)*8]);
      }
    }
    bf16x8 af[4], bfr[4];
    #pragma unroll
    for (int i=0;i<4;++i){
      af[i]  = *(const bf16x8*)&lsA[cur][(wm*64+i*16+lr)*32 + lk*8];
      bfr[i] = *(const bf16x8*)&lsB[cur][(wn*64+i*16+lr)*32 + lk*8];
    }
    #pragma unroll
    for (int i=0;i<4;++i)
      #pragma unroll
      for (int j=0;j<4;++j)
        acc[i][j] = __builtin_amdgcn_mfma_f32_16x16x32_bf16(af[i], bfr[j], acc[i][j], 0,0,0);
    cur ^= 1;
  }
  // epilogue: C/D layout col=lane&15, row=(lane>>4)*4+r
  #pragma unroll
  for (int i=0;i<4;++i)
    #pragma unroll
    for (int j=0;j<4;++j)
      #pragma unroll
      for (int r=0;r<4;++r){
        const int m = m0 + wm*64 + i*16 + lk*4 + r;
        const int n = n0 + wn*64 + j*16 + lr;
        const float v = acc[i][j][r];
        const int b = m>>11, s = m&2047, h = n>>6, dk = n&63;
        size_t addr;
        if (mode == 0) addr = (((size_t)(b*NH+h))*NS + s)*NDK + dk;     // [b,h,s,dk]
        else           addr = (((size_t)(b*NH+h))*NDK + dk)*NS + s;     // [b,h,dk,s]
        out[addr] = f2bf(v);
      }
}

// ---------------- output projection: 128x128 m97 core + fused residual ----------------
__global__ __launch_bounds__(256) void gemm_out(const short* __restrict__ Attn, const short* __restrict__ Wo,
                                                const float* __restrict__ Qin, float* __restrict__ proj){
  __shared__ short lsA[2][4096];
  __shared__ short lsB[2][4096];
  const int tid = threadIdx.x;
  const int hw = blockIdx.x;                        // 256 blocks
  const int logical = (hw & 7)*32 + (hw >> 3);      // bijective (256 = 8*32)
  const int my = logical >> 3, nx = logical & 7;
  const int m0 = my*128, n0 = nx*128;
  const short* gA = Attn + (size_t)m0*1024;
  const short* gB = Wo + (size_t)n0*1024;
  const int srow = tid>>2, scol = (tid&3)*8;
  const int w = tid>>6, lane = tid&63, lr = lane&15, lk = lane>>4;
  const int wm = w>>1, wn = w&1;

  f32x4 acc[4][4];
  #pragma unroll
  for (int i=0;i<4;++i)
    #pragma unroll
    for (int j=0;j<4;++j) acc[i][j] = (f32x4){0.f,0.f,0.f,0.f};

  #pragma unroll
  for (int r=0;r<2;++r){
    gload_lds16(gA + (size_t)(r*64+srow)*1024 + scol, &lsA[0][(r*256+tid)*8]);
    gload_lds16(gB + (size_t)(r*64+srow)*1024 + scol, &lsB[0][(r*256+tid)*8]);
  }
  int cur = 0;
  for (int ks=0; ks<32; ++ks){
    __syncthreads();
    if (ks+1 < 32){
      const int k0 = (ks+1)*32;
      #pragma unroll
      for (int r=0;r<2;++r){
        gload_lds16(gA + (size_t)(r*64+srow)*1024 + k0 + scol, &lsA[cur^1][(r*256+tid)*8]);
        gload_lds16(gB + (size_t)(r*64+srow)*1024 + k0 + scol, &lsB[cur^1][(r*256+tid)*8]);
      }
    }
    bf16x8 af[4], bfr[4];
    #pragma unroll
    for (int i=0;i<4;++i){
      af[i]  = *(const bf16x8*)&lsA[cur][(wm*64+i*16+lr)*32 + lk*8];
      bfr[i] = *(const bf16x8*)&lsB[cur][(wn*64+i*16+lr)*32 + lk*8];
    }
    #pragma unroll
    for (int i=0;i<4;++i)
      #pragma unroll
      for (int j=0;j<4;++j)
        acc[i][j] = __builtin_amdgcn_mfma_f32_16x16x32_bf16(af[i], bfr[j], acc[i][j], 0,0,0);
    cur ^= 1;
  }
  #pragma unroll
  for (int i=0;i<4;++i)
    #pragma unroll
    for (int j=0;j<4;++j)
      #pragma unroll
      for (int r=0;r<4;++r){
        const int m = m0 + wm*64 + i*16 + lk*4 + r;
        const int n = n0 + wn*64 + j*16 + lr;
        proj[(size_t)m*1024 + n] = acc[i][j][r] + Qin[(size_t)m*1024 + n];   // fused residual
      }
}

// ---------------- flash attention: LDS-staged K/V + in-block 2-way kv-split ----------------
// Grid: 512 blocks = (b, h, qblk-of-128), 512 threads -> 2 blocks/CU, 4 waves/SIMD.
// Warp w: q rows (w&3)*32, kv half (w>>2). Pairs (w,w+4) combine via LDS (R2-verified).
// K/V staged double-buffered per half via global_load_lds w/ pre-swizzled source.
// Mask hoisted: per-tile ballot words precomputed into LDS once.
__global__ __launch_bounds__(512) void attn_k(const short* __restrict__ qh, const short* __restrict__ kh,
                                              const short* __restrict__ vT, const int* __restrict__ mask,
                                              unsigned short* __restrict__ attn){
  // LDS map: K [0,32K): half*8192 + buf*16384 ; V [32K,64K): +32768
  // smask u64[32] @65536. Combine reuse (after barrier): smm/sml @32768, excg warp areas @ w*8192.
  __shared__ char sb[66048];
  const int bid = blockIdx.x;
  const int qb = bid & 15, h = (bid>>4)&15, b = bid>>8;
  const int tid = threadIdx.x, w = tid>>6, lane = tid&63;
  const int ql = lane & 31, hi = lane>>5;
  const int qw = w & 3, half = w>>2;
  const int bh = b*NH + h;
  const int q0 = qb*128 + qw*32;
  const float C2 = 0.18033688f;   // 0.125 * log2(e)

  // staging addressing: D = linear dest byte in 8KB tile; S = pre-swizzled source byte
  const int D = tid*16;                          // 512 threads x 16B = 8KB tile
  const int strow = D>>7;                        // tile row (kv for K, dk for V)
  const int S = D ^ ((strow&7)<<4);
  const char* ksrc = (const char*)(kh + (size_t)bh*NS*NDK) + S;                    // + kv*128
  const char* vsrc = (const char*)(vT + ((size_t)bh*NDK + strow)*NS) + (S & 127);  // + kv*2

  // Q as B-fragments: lane holds Q[q0+ql][kp*16 + hi*8 + j]
  const short* qrow = qh + ((size_t)bh*NS + q0 + ql)*NDK + hi*8;
  bf16x8 qf[4];
  #pragma unroll
  for (int kp=0;kp<4;++kp) qf[kp] = *(const bf16x8*)(qrow + kp*16);

  const int* mrow = mask + b*NS;
  unsigned long long* smask = (unsigned long long*)(sb + 65536);

  // prologue: stage tile 0 of both halves into buf 0
  gload_lds16(ksrc,                      sb + D);
  gload_lds16(ksrc + (size_t)1024*128,   sb + 8192 + D);
  gload_lds16(vsrc,                      sb + 32768 + D);
  gload_lds16(vsrc + (size_t)1024*2,     sb + 32768 + 8192 + D);

  // mask precompute: warp w handles kv-tiles w*4..w*4+3 (ballot words -> LDS)
  #pragma unroll
  for (int j=0;j<4;++j){
    const int gt = w*4 + j;
    const unsigned long long bal = __ballot(mrow[gt*64 + lane] != 0);
    if (lane == 0) smask[gt] = bal;
  }

  f32x16 o0, o1;
  #pragma unroll
  for (int r=0;r<16;++r){ o0[r]=0.f; o1[r]=0.f; }
  float mrun = -1e30f, lrun = 0.f;

  const int swz = (ql&7)<<4;

  for (int t=0; t<16; ++t){
    const int buf = (t&1)*16384;
    __syncthreads();                              // staged loads for buf[t&1] arrived
    if (t+1 < 16){
      const int nbuf = ((t+1)&1)*16384;
      const size_t kvn0 = (size_t)(t+1)*64, kvn1 = 1024 + kvn0;
      gload_lds16(ksrc + kvn0*128, sb + nbuf + D);
      gload_lds16(ksrc + kvn1*128, sb + nbuf + 8192 + D);
      gload_lds16(vsrc + kvn0*2,   sb + 32768 + nbuf + D);
      gload_lds16(vsrc + kvn1*2,   sb + 32768 + nbuf + 8192 + D);
    }
    const unsigned long long m64 = smask[half*16 + t];
    const unsigned mw0 = (unsigned)m64, mw1 = (unsigned)(m64>>32);
    const bool allm = (~m64) == 0ull;

    const char* kb = sb + buf + half*8192;
    const char* vb = sb + 32768 + buf + half*8192;

    bf16x8 kf[8];
    #pragma unroll
    for (int kvh=0;kvh<2;++kvh)
      #pragma unroll
      for (int kp=0;kp<4;++kp)
        kf[kvh*4+kp] = *(const bf16x8*)(kb + (((kvh*32+ql)*128 + kp*32 + hi*16) ^ swz));

    f32x16 s0, s1;
    #pragma unroll
    for (int r=0;r<16;++r){ s0[r]=0.f; s1[r]=0.f; }
    #pragma unroll
    for (int kp=0;kp<4;++kp){
      s0 = mfma32(kf[kp],   qf[kp], s0);
      s1 = mfma32(kf[4+kp], qf[kp], s1);
    }

    float t16[16];
    #pragma unroll
    for (int r=0;r<16;++r) t16[r] = fmaxf(s0[r], s1[r]);
    #pragma unroll
    for (int st=8; st>=1; st>>=1)
      #pragma unroll
      for (int r=0;r<st;++r) t16[r] = fmaxf(t16[r], t16[r+st]);
    const float tm = fmaxf(t16[0], __shfl_xor(t16[0], 32, 64));

    // T13 defer-max
    if (!__all(tm - mrun <= 32.f)){
      const float mnew = fmaxf(mrun, tm);
      const float fac  = fexp2((mrun - mnew)*C2);
      mrun = mnew;
      #pragma unroll
      for (int r=0;r<16;++r){ o0[r]*=fac; o1[r]*=fac; }
      lrun *= fac;
    }
    const float nb = mrun*C2;

    bf16x8 vf[8];
    #pragma unroll
    for (int dh=0;dh<2;++dh)
      #pragma unroll
      for (int c=0;c<4;++c)
        vf[dh*4+c] = *(const bf16x8*)(vb + (((dh*32+ql)*128 + c*32 + hi*16) ^ swz));

    float psum = 0.f;
    #pragma unroll
    for (int kvh=0; kvh<2; ++kvh){
      const f32x16& ss = kvh ? s1 : s0;
      const unsigned mw = kvh ? mw1 : mw0;
      unsigned pwd[8];
      float ps0 = 0.f, ps1 = 0.f;
      #pragma unroll
      for (int i=0;i<8;++i){
        const int bp0 = ((2*i)&3) + 8*((2*i)>>2);   // {0,2,8,10,16,18,24,26}
        float p0 = fexp2(ss[2*i]*C2   - nb);
        float p1 = fexp2(ss[2*i+1]*C2 - nb);
        if (!allm){
          p0 = ((mw >> (bp0     + 4*hi)) & 1u) ? p0 : 0.f;
          p1 = ((mw >> (bp0 + 1 + 4*hi)) & 1u) ? p1 : 0.f;
        }
        ps0 += p0; ps1 += p1;
        pwd[i] = cvtpk_bf16(p0, p1);
      }
      psum += ps0 + ps1;
      swap32(pwd[0], pwd[2]);
      swap32(pwd[1], pwd[3]);
      swap32(pwd[4], pwd[6]);
      swap32(pwd[5], pwd[7]);
      u32x4 c0w = {pwd[0], pwd[1], pwd[2], pwd[3]};
      u32x4 c1w = {pwd[4], pwd[5], pwd[6], pwd[7]};
      bf16x8 pf0 = __builtin_bit_cast(bf16x8, c0w);
      bf16x8 pf1 = __builtin_bit_cast(bf16x8, c1w);
      o0 = mfma32(vf[2*kvh],       pf0, o0);
      o1 = mfma32(vf[4 + 2*kvh],   pf0, o1);
      o0 = mfma32(vf[2*kvh + 1],   pf1, o0);
      o1 = mfma32(vf[4 + 2*kvh+1], pf1, o1);
    }
    psum += __shfl_xor(psum, 32, 64);
    lrun += psum;
  }

  // ---- combine the two kv halves (pairs w <-> w+4 share q rows) ----
  __syncthreads();                                // all staging reads done; LDS reusable
  float* smm = (float*)(sb + 32768);              // [8][32]
  float* sml = (float*)(sb + 32768 + 1024);
  if (hi == 0){ smm[w*32 + ql] = mrun; sml[w*32 + ql] = lrun; }
  __syncthreads();
  const float pmv = smm[(w^4)*32 + ql], plv = sml[(w^4)*32 + ql];
  const float mfin = fmaxf(mrun, pmv);
  const float facS = fexp2((mrun - mfin)*C2);
  if (w >= 4){
    float* eg = (float*)(sb + (size_t)(w-4)*8192);
    #pragma unroll
    for (int r=0;r<16;++r){
      eg[ql + 32*(hi*16 + r)]        = o0[r]*facS;
      eg[ql + 32*(hi*16 + r) + 1024] = o1[r]*facS;
    }
  }
  __syncthreads();
  if (w < 4){
    float* eg = (float*)(sb + (size_t)w*8192);
    #pragma unroll
    for (int r=0;r<16;++r){
      o0[r] = o0[r]*facS + eg[ql + 32*(hi*16 + r)];
      o1[r] = o1[r]*facS + eg[ql + 32*(hi*16 + r) + 1024];
    }
    const float facP = fexp2((pmv - mfin)*C2);
    const float lfin = lrun*facS + plv*facP;
    const float inv = 1.f / lfin;
    asm volatile("s_waitcnt lgkmcnt(0)" ::: "memory");   // reads done before overwrite
    char* ep = sb + (size_t)w*8192;
    #pragma unroll
    for (int dh=0; dh<2; ++dh){
      const f32x16& oo = dh ? o1 : o0;
      #pragma unroll
      for (int i=0;i<8;++i){
        const int d0 = ((2*i)&3) + 8*((2*i)>>2) + 4*hi + dh*32;
        const unsigned pk = cvtpk_bf16(oo[2*i]*inv, oo[2*i+1]*inv);
        *(unsigned*)(ep + (((ql*128) + d0*2) ^ ((ql&7)<<4))) = pk;
      }
    }
    asm volatile("s_waitcnt lgkmcnt(0)" ::: "memory");
    #pragma unroll
    for (int seg=0; seg<4; ++seg){
      const int qq = seg*8 + (lane>>3), dc = (lane&7)*8;
      bf16x8 vv = *(const bf16x8*)(ep + (((qq*128) + dc*2) ^ ((qq&7)<<4)));
      *(bf16x8*)(attn + ((size_t)b*NS + q0 + qq)*ND + h*NDK + dc) = vv;
    }
  }
}

// ---------------- LayerNorm (1 wave per row; residual already in proj) ----------------
__global__ __launch_bounds__(256) void ln_k(const float* __restrict__ proj,
                                            const float* __restrict__ gamma, const float* __restrict__ beta,
                                            float* __restrict__ out){
  const int row = blockIdx.x*4 + (threadIdx.x>>6);
  const int lane = threadIdx.x & 63;
  const float4* pp = (const float4*)(proj + (size_t)row*ND);
  float4 x[4];
  float sum = 0.f;
  #pragma unroll
  for (int i=0;i<4;++i){
    x[i] = pp[lane + i*64];
    sum += x[i].x + x[i].y + x[i].z + x[i].w;
  }
  #pragma unroll
  for (int off=32; off>=1; off>>=1) sum += __shfl_xor(sum, off, 64);
  const float mu = sum * (1.f/1024.f);
  float vs = 0.f;
  #pragma unroll
  for (int i=0;i<4;++i){
    float d0=x[i].x-mu, d1=x[i].y-mu, d2=x[i].z-mu, d3=x[i].w-mu;
    vs += d0*d0 + d1*d1 + d2*d2 + d3*d3;
  }
  #pragma unroll
  for (int off=32; off>=1; off>>=1) vs += __shfl_xor(vs, off, 64);
  const float rstd = rsqrtf(vs*(1.f/1024.f) + 1e-5f);
  #pragma unroll
  for (int i=0;i<4;++i){
    const float4 g  = ((const float4*)gamma)[lane + i*64];
    const float4 be = ((const float4*)beta)[lane + i*64];
    float4 y;
    y.x = (x[i].x-mu)*rstd*g.x + be.x;
    y.y = (x[i].y-mu)*rstd*g.y + be.y;
    y.z = (x[i].z-mu)*rstd*g.z + be.z;
    y.w = (x[i].w-mu)*rstd*g.w + be.w;
    ((float4*)(out + (size_t)row*ND))[lane + i*64] = y;
  }
}

// ---------------- launch ----------------
// ws layout (64 MB):
//   [0,8MB)   Wbf: Wq,Wk,Wv,Wo bf16
//   [8,32MB)  Xbf: Qbf,Kbf,Vbf ; later: proj f32 (16MB, after gemm_qkv)
//   [32,40)   qh bf16 [b,h,s,dk]
//   [40,48)   kh bf16 [b,h,s,dk]
//   [48,56)   vT bf16 [b,h,dk,s]
//   [56,64)   attn bf16 [b,s,d]
extern "C" void kernel_launch(void* const* d_in, const int* in_sizes, int n_in,
                              void* d_out, int out_size, void* d_ws, size_t ws_size,
                              hipStream_t stream){
  const float* Q    = (const float*)d_in[0];
  const float* K    = (const float*)d_in[1];
  const float* V    = (const float*)d_in[2];
  const int*   mask = (const int*)  d_in[3];
  const float* Wq   = (const float*)d_in[4];
  const float* Wk   = (const float*)d_in[5];
  const float* Wv   = (const float*)d_in[6];
  const float* Wo   = (const float*)d_in[7];
  const float* gam  = (const float*)d_in[8];
  const float* bet  = (const float*)d_in[9];
  float* out = (float*)d_out;
  char* ws = (char*)d_ws;

  unsigned short* Wbf  = (unsigned short*)(ws);
  unsigned short* Xbf  = (unsigned short*)(ws + (size_t)(8u<<20));
  unsigned short* qhp  = (unsigned short*)(ws + (size_t)(32u<<20));
  unsigned short* khp  = (unsigned short*)(ws + (size_t)(40u<<20));
  unsigned short* vTp  = (unsigned short*)(ws + (size_t)(48u<<20));
  unsigned short* attb = (unsigned short*)(ws + (size_t)(56u<<20));
  float* proj  = (float*)(ws + (size_t)(8u<<20));          // aliases Xbf (dead after gemm_qkv)

  prep_k<<<16384,256,0,stream>>>(Q, K, V, Wq, Wk, Wv, Wo, Xbf, Wbf);

  gemm_qkv<<<768,256,0,stream>>>((const short*)Xbf, (const short*)Wbf, qhp, khp, vTp);

  attn_k<<<512,512,0,stream>>>((const short*)qhp, (const short*)khp, (const short*)vTp, mask, attb);

  gemm_out<<<256,256,0,stream>>>((const short*)attb, (const short*)(Wbf + (3u<<20)), Q, proj);

  ln_k<<<1024,256,0,stream>>>(proj, gam, bet, out);
}

// Round 9
// 166.359 us; speedup vs baseline: 1.0412x; 1.0412x over previous
//
#include <hip/hip_runtime.h>
#include <hip/hip_bf16.h>
#include <stdint.h>

// Problem constants
#define NB 2
#define NS 2048
#define ND 1024
#define NH 16
#define NDK 64
#define NM (NB*NS)   // 4096 rows

using bf16x8 = __attribute__((ext_vector_type(8))) short;   // 8 bf16 (4 VGPRs)
using f32x4  = __attribute__((ext_vector_type(4))) float;   // 4 fp32
using f32x16 = __attribute__((ext_vector_type(16))) float;  // 16 fp32
using u32x4  = __attribute__((ext_vector_type(4))) unsigned;

__device__ __forceinline__ unsigned short f2bf(float f){
  unsigned u = __float_as_uint(f);
  u += 0x7fffu + ((u>>16)&1u);          // RNE
  return (unsigned short)(u>>16);
}

__device__ __forceinline__ void gload_lds16(const void* g, void* l){
  __builtin_amdgcn_global_load_lds((const __attribute__((address_space(1))) void*)g,
                                   (__attribute__((address_space(3))) void*)l, 16, 0, 0);
}

__device__ __forceinline__ float fexp2(float x){
#if __has_builtin(__builtin_amdgcn_exp2f)
  return __builtin_amdgcn_exp2f(x);
#else
  return __expf(x * 0.69314718056f);
#endif
}

__device__ __forceinline__ unsigned cvtpk_bf16(float lo, float hi){
  unsigned r;
  asm("v_cvt_pk_bf16_f32 %0, %1, %2" : "=v"(r) : "v"(lo), "v"(hi));
  return r;
}

__device__ __forceinline__ void swap32(unsigned &a, unsigned &b){
#if __has_builtin(__builtin_amdgcn_permlane32_swap)
  auto rr = __builtin_amdgcn_permlane32_swap((int)a, (int)b, false, false);
  a = (unsigned)rr[0]; b = (unsigned)rr[1];
#else
  const bool lo = (threadIdx.x & 32) == 0;
  unsigned sa = (unsigned)__shfl_xor((int)a, 32, 64);
  unsigned sb = (unsigned)__shfl_xor((int)b, 32, 64);
  unsigned na = lo ? a : sb;
  unsigned nb = lo ? sa : b;
  a = na; b = nb;
#endif
}

__device__ __forceinline__ f32x16 mfma32(bf16x8 a, bf16x8 b, f32x16 c){
  return __builtin_amdgcn_mfma_f32_32x32x16_bf16(a, b, c, 0, 0, 0);
}

// ---------------- prep: W-only fp32->bf16 cast (Q/K/V now consumed as f32 by gemm_qkv) ----
__global__ __launch_bounds__(256) void prep_k(const float* __restrict__ Wq, const float* __restrict__ Wk,
                                              const float* __restrict__ Wv, const float* __restrict__ Wo,
                                              unsigned short* __restrict__ Wbf){
  const int bid = blockIdx.x;                       // 4096 blocks
  const int which = bid >> 10;
  const float* src = (which==0) ? Wq : (which==1) ? Wk : (which==2) ? Wv : Wo;
  unsigned short* dst = Wbf + ((size_t)which << 20);
  const int i = (bid & 1023)*256 + threadIdx.x;
  float4 v = ((const float4*)src)[i];
  ushort4 o;
  o.x = f2bf(v.x); o.y = f2bf(v.y); o.z = f2bf(v.z); o.w = f2bf(v.w);
  ((ushort4*)dst)[i] = o;
}

// ---------------- QKV GEMM: 128x128, A staged as f32 (in-kernel cvt), XCD-chunked ----------
// A tile f32 16KB x2buf + B bf16 8KB x2buf = 48KB LDS -> 3 blocks/CU kept.
__global__ __launch_bounds__(256) void gemm_qkv(const float* __restrict__ Qf, const float* __restrict__ Kf,
                                                const float* __restrict__ Vf, const short* __restrict__ Wbf,
                                                unsigned short* __restrict__ qh, unsigned short* __restrict__ kh,
                                                unsigned short* __restrict__ vT){
  __shared__ float lsA[2][4096];   // [buf][128 rows x 32 k] f32
  __shared__ short lsB[2][4096];   // [buf][128 rows x 32 k] bf16
  const int tid = threadIdx.x;
  const int hw = blockIdx.x;                         // 768 blocks
  const int logical = (hw & 7)*96 + (hw >> 3);       // bijective (768 = 8*96)
  const int z = logical >> 8, rem = logical & 255;
  const int my = rem >> 3, nx = rem & 7;
  const float* A = (z==0) ? Qf : (z==1) ? Kf : Vf;
  const short* W = Wbf + (size_t)z*ND*ND;
  unsigned short* out = (z==0) ? qh : (z==1) ? kh : vT;
  const int mode = (z==2) ? 1 : 0;
  const int m0 = my*128, n0 = nx*128;

  const float* gA = A + (size_t)m0*1024;
  const short* gB = W + (size_t)n0*1024;
  // B staging: 4 threads/row x 16B ; A staging: 8 threads/row x 16B (4 floats), 4 passes
  const int bsrow = tid>>2, bscol = (tid&3)*8;
  const int asrow = tid>>3, ascol = (tid&7)*4;
  const int w = tid>>6, lane = tid&63, lr = lane&15, lk = lane>>4;
  const int wm = w>>1, wn = w&1;

  f32x4 acc[4][4];
  #pragma unroll
  for (int i=0;i<4;++i)
    #pragma unroll
    for (int j=0;j<4;++j) acc[i][j] = (f32x4){0.f,0.f,0.f,0.f};

  // prologue: stage k-step 0 into buf 0
  #pragma unroll
  for (int r=0;r<4;++r)
    gload_lds16(gA + (size_t)(r*32+asrow)*1024 + ascol, &lsA[0][r*1024 + asrow*32 + ascol]);
  #pragma unroll
  for (int r=0;r<2;++r)
    gload_lds16(gB + (size_t)(r*64+bsrow)*1024 + bscol, &lsB[0][(r*256+tid)*8]);

  int cur = 0;
  for (int ks=0; ks<32; ++ks){
    __syncthreads();
    if (ks+1 < 32){
      const int k0 = (ks+1)*32;
      #pragma unroll
      for (int r=0;r<4;++r)
        gload_lds16(gA + (size_t)(r*32+asrow)*1024 + k0 + ascol, &lsA[cur^1][r*1024 + asrow*32 + ascol]);
      #pragma unroll
      for (int r=0;r<2;++r)
        gload_lds16(gB + (size_t)(r*64+bsrow)*1024 + k0 + bscol, &lsB[cur^1][(r*256+tid)*8]);
    }
    bf16x8 af[4], bfr[4];
    #pragma unroll
    for (int i=0;i<4;++i){
      const float* ap = &lsA[cur][(wm*64+i*16+lr)*32 + lk*8];
      const float4 lo = *(const float4*)ap;
      const float4 hi = *(const float4*)(ap+4);
      u32x4 aw = { cvtpk_bf16(lo.x, lo.y), cvtpk_bf16(lo.z, lo.w),
                   cvtpk_bf16(hi.x, hi.y), cvtpk_bf16(hi.z, hi.w) };
      af[i] = __builtin_bit_cast(bf16x8, aw);
      bfr[i] = *(const bf16x8*)&lsB[cur][(wn*64+i*16+lr)*32 + lk*8];
    }
    #pragma unroll
    for (int i=0;i<4;++i)
      #pragma unroll
      for (int j=0;j<4;++j)
        acc[i][j] = __builtin_amdgcn_mfma_f32_16x16x32_bf16(af[i], bfr[j], acc[i][j], 0,0,0);
    cur ^= 1;
  }
  // epilogue: C/D layout col=lane&15, row=(lane>>4)*4+r
  #pragma unroll
  for (int i=0;i<4;++i)
    #pragma unroll
    for (int j=0;j<4;++j)
      #pragma unroll
      for (int r=0;r<4;++r){
        const int m = m0 + wm*64 + i*16 + lk*4 + r;
        const int n = n0 + wn*64 + j*16 + lr;
        const float v = acc[i][j][r];
        const int b = m>>11, s = m&2047, h = n>>6, dk = n&63;
        size_t addr;
        if (mode == 0) addr = (((size_t)(b*NH+h))*NS + s)*NDK + dk;     // [b,h,s,dk]
        else           addr = (((size_t)(b*NH+h))*NDK + dk)*NS + s;     // [b,h,dk,s]
        out[addr] = f2bf(v);
      }
}

// ---------------- output projection: 128x128 m97 core + fused residual ----------------
__global__ __launch_bounds__(256) void gemm_out(const short* __restrict__ Attn, const short* __restrict__ Wo,
                                                const float* __restrict__ Qin, float* __restrict__ proj){
  __shared__ short lsA[2][4096];
  __shared__ short lsB[2][4096];
  const int tid = threadIdx.x;
  const int hw = blockIdx.x;                        // 256 blocks
  const int logical = (hw & 7)*32 + (hw >> 3);      // bijective (256 = 8*32)
  const int my = logical >> 3, nx = logical & 7;
  const int m0 = my*128, n0 = nx*128;
  const short* gA = Attn + (size_t)m0*1024;
  const short* gB = Wo + (size_t)n0*1024;
  const int srow = tid>>2, scol = (tid&3)*8;
  const int w = tid>>6, lane = tid&63, lr = lane&15, lk = lane>>4;
  const int wm = w>>1, wn = w&1;

  f32x4 acc[4][4];
  #pragma unroll
  for (int i=0;i<4;++i)
    #pragma unroll
    for (int j=0;j<4;++j) acc[i][j] = (f32x4){0.f,0.f,0.f,0.f};

  #pragma unroll
  for (int r=0;r<2;++r){
    gload_lds16(gA + (size_t)(r*64+srow)*1024 + scol, &lsA[0][(r*256+tid)*8]);
    gload_lds16(gB + (size_t)(r*64+srow)*1024 + scol, &lsB[0][(r*256+tid)*8]);
  }
  int cur = 0;
  for (int ks=0; ks<32; ++ks){
    __syncthreads();
    if (ks+1 < 32){
      const int k0 = (ks+1)*32;
      #pragma unroll
      for (int r=0;r<2;++r){
        gload_lds16(gA + (size_t)(r*64+srow)*1024 + k0 + scol, &lsA[cur^1][(r*256+tid)*8]);
        gload_lds16(gB + (size_t)(r*64+srow)*1024 + k0 + scol, &lsB[cur^1][(r*256+tid)*8]);
      }
    }
    bf16x8 af[4], bfr[4];
    #pragma unroll
    for (int i=0;i<4;++i){
      af[i]  = *(const bf16x8*)&lsA[cur][(wm*64+i*16+lr)*32 + lk*8];
      bfr[i] = *(const bf16x8*)&lsB[cur][(wn*64+i*16+lr)*32 + lk*8];
    }
    #pragma unroll
    for (int i=0;i<4;++i)
      #pragma unroll
      for (int j=0;j<4;++j)
        acc[i][j] = __builtin_amdgcn_mfma_f32_16x16x32_bf16(af[i], bfr[j], acc[i][j], 0,0,0);
    cur ^= 1;
  }
  #pragma unroll
  for (int i=0;i<4;++i)
    #pragma unroll
    for (int j=0;j<4;++j)
      #pragma unroll
      for (int r=0;r<4;++r){
        const int m = m0 + wm*64 + i*16 + lk*4 + r;
        const int n = n0 + wn*64 + j*16 + lr;
        proj[(size_t)m*1024 + n] = acc[i][j][r] + Qin[(size_t)m*1024 + n];   // fused residual
      }
}

// ---------------- flash attention: LDS-staged K/V + in-block 2-way kv-split ----------------
// Grid: 512 blocks (XCD-chunked: each XCD owns 4 complete (b,h) heads), 512 threads.
// LDS EXACTLY 64KB (R8 post-mortem: 66KB blocked 2-block co-residency).
// Warp w: q rows (w&3)*32, kv half (w>>2). Pairs (w,w+4) combine via LDS.
__global__ __launch_bounds__(512) void attn_k(const short* __restrict__ qh, const short* __restrict__ kh,
                                              const short* __restrict__ vT, const int* __restrict__ mask,
                                              unsigned short* __restrict__ attn){
  // LDS map: K [0,32K): half*8192 + buf*16384 ; V [32K,64K): +32768
  __shared__ char sb[65536];
  const int hw = blockIdx.x;                         // 512 blocks
  const int logical = (hw & 7)*64 + (hw >> 3);       // bijective (512 = 8*64)
  const int qb = logical & 15, h = (logical>>4)&15, b = logical>>8;
  const int tid = threadIdx.x, w = tid>>6, lane = tid&63;
  const int ql = lane & 31, hi = lane>>5;
  const int qw = w & 3, half = w>>2;
  const int bh = b*NH + h;
  const int q0 = qb*128 + qw*32;
  const float C2 = 0.18033688f;   // 0.125 * log2(e)

  // staging addressing: D = linear dest byte in 8KB tile; S = pre-swizzled source byte
  const int D = tid*16;                          // 512 threads x 16B = 8KB tile
  const int strow = D>>7;                        // tile row (kv for K, dk for V)
  const int S = D ^ ((strow&7)<<4);
  const char* ksrc = (const char*)(kh + (size_t)bh*NS*NDK) + S;                    // + kv*128
  const char* vsrc = (const char*)(vT + ((size_t)bh*NDK + strow)*NS) + (S & 127);  // + kv*2

  // Q as B-fragments: lane holds Q[q0+ql][kp*16 + hi*8 + j]
  const short* qrow = qh + ((size_t)bh*NS + q0 + ql)*NDK + hi*8;
  bf16x8 qf[4];
  #pragma unroll
  for (int kp=0;kp<4;++kp) qf[kp] = *(const bf16x8*)(qrow + kp*16);

  const int* mrow = mask + b*NS + half*1024;

  // prologue: stage tile 0 of both halves into buf 0
  gload_lds16(ksrc,                      sb + D);
  gload_lds16(ksrc + (size_t)1024*128,   sb + 8192 + D);
  gload_lds16(vsrc,                      sb + 32768 + D);
  gload_lds16(vsrc + (size_t)1024*2,     sb + 32768 + 8192 + D);

  f32x16 o0, o1;
  #pragma unroll
  for (int r=0;r<16;++r){ o0[r]=0.f; o1[r]=0.f; }
  float mrun = -1e30f, lrun = 0.f;

  const int swz = (ql&7)<<4;

  for (int t=0; t<16; ++t){
    const int buf = (t&1)*16384;
    __syncthreads();                              // staged loads for buf[t&1] arrived
    if (t+1 < 16){
      const int nbuf = ((t+1)&1)*16384;
      const size_t kvn0 = (size_t)(t+1)*64, kvn1 = 1024 + kvn0;
      gload_lds16(ksrc + kvn0*128, sb + nbuf + D);
      gload_lds16(ksrc + kvn1*128, sb + nbuf + 8192 + D);
      gload_lds16(vsrc + kvn0*2,   sb + 32768 + nbuf + D);
      gload_lds16(vsrc + kvn1*2,   sb + 32768 + nbuf + 8192 + D);
    }
    const unsigned long long bal = __ballot(mrow[t*64 + lane] != 0);
    const unsigned mw0 = (unsigned)bal, mw1 = (unsigned)(bal>>32);
    const bool allm = (~bal) == 0ull;

    const char* kb = sb + buf + half*8192;
    const char* vb = sb + 32768 + buf + half*8192;

    bf16x8 kf[8];
    #pragma unroll
    for (int kvh=0;kvh<2;++kvh)
      #pragma unroll
      for (int kp=0;kp<4;++kp)
        kf[kvh*4+kp] = *(const bf16x8*)(kb + (((kvh*32+ql)*128 + kp*32 + hi*16) ^ swz));

    f32x16 s0, s1;
    #pragma unroll
    for (int r=0;r<16;++r){ s0[r]=0.f; s1[r]=0.f; }
    __builtin_amdgcn_s_setprio(1);
    #pragma unroll
    for (int kp=0;kp<4;++kp){
      s0 = mfma32(kf[kp],   qf[kp], s0);
      s1 = mfma32(kf[4+kp], qf[kp], s1);
    }
    __builtin_amdgcn_s_setprio(0);

    float t16[16];
    #pragma unroll
    for (int r=0;r<16;++r) t16[r] = fmaxf(s0[r], s1[r]);
    #pragma unroll
    for (int st=8; st>=1; st>>=1)
      #pragma unroll
      for (int r=0;r<st;++r) t16[r] = fmaxf(t16[r], t16[r+st]);
    const float tm = fmaxf(t16[0], __shfl_xor(t16[0], 32, 64));

    // T13 defer-max
    if (!__all(tm - mrun <= 32.f)){
      const float mnew = fmaxf(mrun, tm);
      const float fac  = fexp2((mrun - mnew)*C2);
      mrun = mnew;
      #pragma unroll
      for (int r=0;r<16;++r){ o0[r]*=fac; o1[r]*=fac; }
      lrun *= fac;
    }
    const float nb = mrun*C2;

    bf16x8 vf[8];
    #pragma unroll
    for (int dh=0;dh<2;++dh)
      #pragma unroll
      for (int c=0;c<4;++c)
        vf[dh*4+c] = *(const bf16x8*)(vb + (((dh*32+ql)*128 + c*32 + hi*16) ^ swz));

    float psum = 0.f;
    #pragma unroll
    for (int kvh=0; kvh<2; ++kvh){
      const f32x16& ss = kvh ? s1 : s0;
      const unsigned mw = kvh ? mw1 : mw0;
      unsigned pwd[8];
      float ps0 = 0.f, ps1 = 0.f;
      #pragma unroll
      for (int i=0;i<8;++i){
        const int bp0 = ((2*i)&3) + 8*((2*i)>>2);   // {0,2,8,10,16,18,24,26}
        float p0 = fexp2(ss[2*i]*C2   - nb);
        float p1 = fexp2(ss[2*i+1]*C2 - nb);
        if (!allm){
          p0 = ((mw >> (bp0     + 4*hi)) & 1u) ? p0 : 0.f;
          p1 = ((mw >> (bp0 + 1 + 4*hi)) & 1u) ? p1 : 0.f;
        }
        ps0 += p0; ps1 += p1;
        pwd[i] = cvtpk_bf16(p0, p1);
      }
      psum += ps0 + ps1;
      swap32(pwd[0], pwd[2]);
      swap32(pwd[1], pwd[3]);
      swap32(pwd[4], pwd[6]);
      swap32(pwd[5], pwd[7]);
      u32x4 c0w = {pwd[0], pwd[1], pwd[2], pwd[3]};
      u32x4 c1w = {pwd[4], pwd[5], pwd[6], pwd[7]};
      bf16x8 pf0 = __builtin_bit_cast(bf16x8, c0w);
      bf16x8 pf1 = __builtin_bit_cast(bf16x8, c1w);
      __builtin_amdgcn_s_setprio(1);
      o0 = mfma32(vf[2*kvh],       pf0, o0);
      o1 = mfma32(vf[4 + 2*kvh],   pf0, o1);
      o0 = mfma32(vf[2*kvh + 1],   pf1, o0);
      o1 = mfma32(vf[4 + 2*kvh+1], pf1, o1);
      __builtin_amdgcn_s_setprio(0);
    }
    psum += __shfl_xor(psum, 32, 64);
    lrun += psum;
  }

  // ---- combine the two kv halves (pairs w <-> w+4 share q rows) ----
  __syncthreads();                                // all staging reads done; LDS reusable
  float* smm = (float*)(sb + 32768);              // [8][32]
  float* sml = (float*)(sb + 32768 + 1024);
  if (hi == 0){ smm[w*32 + ql] = mrun; sml[w*32 + ql] = lrun; }
  __syncthreads();
  const float pmv = smm[(w^4)*32 + ql], plv = sml[(w^4)*32 + ql];
  const float mfin = fmaxf(mrun, pmv);
  const float facS = fexp2((mrun - mfin)*C2);
  if (w >= 4){
    float* eg = (float*)(sb + (size_t)(w-4)*8192);
    #pragma unroll
    for (int r=0;r<16;++r){
      eg[ql + 32*(hi*16 + r)]        = o0[r]*facS;
      eg[ql + 32*(hi*16 + r) + 1024] = o1[r]*facS;
    }
  }
  __syncthreads();
  if (w < 4){
    float* eg = (float*)(sb + (size_t)w*8192);
    #pragma unroll
    for (int r=0;r<16;++r){
      o0[r] = o0[r]*facS + eg[ql + 32*(hi*16 + r)];
      o1[r] = o1[r]*facS + eg[ql + 32*(hi*16 + r) + 1024];
    }
    const float facP = fexp2((pmv - mfin)*C2);
    const float lfin = lrun*facS + plv*facP;
    const float inv = 1.f / lfin;
    asm volatile("s_waitcnt lgkmcnt(0)" ::: "memory");   // reads done before overwrite
    char* ep = sb + (size_t)w*8192;
    #pragma unroll
    for (int dh=0; dh<2; ++dh){
      const f32x16& oo = dh ? o1 : o0;
      #pragma unroll
      for (int i=0;i<8;++i){
        const int d0 = ((2*i)&3) + 8*((2*i)>>2) + 4*hi + dh*32;
        const unsigned pk = cvtpk_bf16(oo[2*i]*inv, oo[2*i+1]*inv);
        *(unsigned*)(ep + (((ql*128) + d0*2) ^ ((ql&7)<<4))) = pk;
      }
    }
    asm volatile("s_waitcnt lgkmcnt(0)" ::: "memory");
    #pragma unroll
    for (int seg=0; seg<4; ++seg){
      const int qq = seg*8 + (lane>>3), dc = (lane&7)*8;
      bf16x8 vv = *(const bf16x8*)(ep + (((qq*128) + dc*2) ^ ((qq&7)<<4)));
      *(bf16x8*)(attn + ((size_t)b*NS + q0 + qq)*ND + h*NDK + dc) = vv;
    }
  }
}

// ---------------- LayerNorm (1 wave per row; residual already in proj) ----------------
__global__ __launch_bounds__(256) void ln_k(const float* __restrict__ proj,
                                            const float* __restrict__ gamma, const float* __restrict__ beta,
                                            float* __restrict__ out){
  const int row = blockIdx.x*4 + (threadIdx.x>>6);
  const int lane = threadIdx.x & 63;
  const float4* pp = (const float4*)(proj + (size_t)row*ND);
  float4 x[4];
  float sum = 0.f;
  #pragma unroll
  for (int i=0;i<4;++i){
    x[i] = pp[lane + i*64];
    sum += x[i].x + x[i].y + x[i].z + x[i].w;
  }
  #pragma unroll
  for (int off=32; off>=1; off>>=1) sum += __shfl_xor(sum, off, 64);
  const float mu = sum * (1.f/1024.f);
  float vs = 0.f;
  #pragma unroll
  for (int i=0;i<4;++i){
    float d0=x[i].x-mu, d1=x[i].y-mu, d2=x[i].z-mu, d3=x[i].w-mu;
    vs += d0*d0 + d1*d1 + d2*d2 + d3*d3;
  }
  #pragma unroll
  for (int off=32; off>=1; off>>=1) vs += __shfl_xor(vs, off, 64);
  const float rstd = rsqrtf(vs*(1.f/1024.f) + 1e-5f);
  #pragma unroll
  for (int i=0;i<4;++i){
    const float4 g  = ((const float4*)gamma)[lane + i*64];
    const float4 be = ((const float4*)beta)[lane + i*64];
    float4 y;
    y.x = (x[i].x-mu)*rstd*g.x + be.x;
    y.y = (x[i].y-mu)*rstd*g.y + be.y;
    y.z = (x[i].z-mu)*rstd*g.z + be.z;
    y.w = (x[i].w-mu)*rstd*g.w + be.w;
    ((float4*)(out + (size_t)row*ND))[lane + i*64] = y;
  }
}

// ---------------- launch ----------------
// ws layout (64 MB):
//   [0,8MB)   Wbf: Wq,Wk,Wv,Wo bf16
//   [8,24MB)  proj f32 (written by gemm_out)
//   [32,40)   qh bf16 [b,h,s,dk]
//   [40,48)   kh bf16 [b,h,s,dk]
//   [48,56)   vT bf16 [b,h,dk,s]
//   [56,64)   attn bf16 [b,s,d]
extern "C" void kernel_launch(void* const* d_in, const int* in_sizes, int n_in,
                              void* d_out, int out_size, void* d_ws, size_t ws_size,
                              hipStream_t stream){
  const float* Q    = (const float*)d_in[0];
  const float* K    = (const float*)d_in[1];
  const float* V    = (const float*)d_in[2];
  const int*   mask = (const int*)  d_in[3];
  const float* Wq   = (const float*)d_in[4];
  const float* Wk   = (const float*)d_in[5];
  const float* Wv   = (const float*)d_in[6];
  const float* Wo   = (const float*)d_in[7];
  const float* gam  = (const float*)d_in[8];
  const float* bet  = (const float*)d_in[9];
  float* out = (float*)d_out;
  char* ws = (char*)d_ws;

  unsigned short* Wbf  = (unsigned short*)(ws);
  unsigned short* qhp  = (unsigned short*)(ws + (size_t)(32u<<20));
  unsigned short* khp  = (unsigned short*)(ws + (size_t)(40u<<20));
  unsigned short* vTp  = (unsigned short*)(ws + (size_t)(48u<<20));
  unsigned short* attb = (unsigned short*)(ws + (size_t)(56u<<20));
  float* proj  = (float*)(ws + (size_t)(8u<<20));

  prep_k<<<4096,256,0,stream>>>(Wq, Wk, Wv, Wo, Wbf);

  gemm_qkv<<<768,256,0,stream>>>(Q, K, V, (const short*)Wbf, qhp, khp, vTp);

  attn_k<<<512,512,0,stream>>>((const short*)qhp, (const short*)khp, (const short*)vTp, mask, attb);

  gemm_out<<<256,256,0,stream>>>((const short*)attb, (const short*)(Wbf + (3u<<20)), Q, proj);

  ln_k<<<1024,256,0,stream>>>(proj, gam, bet, out);
}

// Round 10
// 161.457 us; speedup vs baseline: 1.0728x; 1.0304x over previous
//
#include <hip/hip_runtime.h>
#include <hip/hip_bf16.h>
#include <stdint.h>

// Problem constants
#define NB 2
#define NS 2048
#define ND 1024
#define NH 16
#define NDK 64
#define NM (NB*NS)   // 4096 rows

using bf16x8 = __attribute__((ext_vector_type(8))) short;   // 8 bf16 (4 VGPRs)
using f32x4  = __attribute__((ext_vector_type(4))) float;   // 4 fp32
using f32x16 = __attribute__((ext_vector_type(16))) float;  // 16 fp32
using u32x4  = __attribute__((ext_vector_type(4))) unsigned;

__device__ __forceinline__ unsigned short f2bf(float f){
  unsigned u = __float_as_uint(f);
  u += 0x7fffu + ((u>>16)&1u);          // RNE
  return (unsigned short)(u>>16);
}

__device__ __forceinline__ void gload_lds16(const void* g, void* l){
  __builtin_amdgcn_global_load_lds((const __attribute__((address_space(1))) void*)g,
                                   (__attribute__((address_space(3))) void*)l, 16, 0, 0);
}

__device__ __forceinline__ float fexp2(float x){
#if __has_builtin(__builtin_amdgcn_exp2f)
  return __builtin_amdgcn_exp2f(x);
#else
  return __expf(x * 0.69314718056f);
#endif
}

__device__ __forceinline__ unsigned cvtpk_bf16(float lo, float hi){
  unsigned r;
  asm("v_cvt_pk_bf16_f32 %0, %1, %2" : "=v"(r) : "v"(lo), "v"(hi));
  return r;
}

__device__ __forceinline__ void swap32(unsigned &a, unsigned &b){
#if __has_builtin(__builtin_amdgcn_permlane32_swap)
  auto rr = __builtin_amdgcn_permlane32_swap((int)a, (int)b, false, false);
  a = (unsigned)rr[0]; b = (unsigned)rr[1];
#else
  const bool lo = (threadIdx.x & 32) == 0;
  unsigned sa = (unsigned)__shfl_xor((int)a, 32, 64);
  unsigned sb = (unsigned)__shfl_xor((int)b, 32, 64);
  unsigned na = lo ? a : sb;
  unsigned nb = lo ? sa : b;
  a = na; b = nb;
#endif
}

__device__ __forceinline__ f32x16 mfma32(bf16x8 a, bf16x8 b, f32x16 c){
  return __builtin_amdgcn_mfma_f32_32x32x16_bf16(a, b, c, 0, 0, 0);
}

// ---------------- prep: W-only fp32->bf16 cast (Q/K/V consumed as f32 by gemm_qkv) ----
__global__ __launch_bounds__(256) void prep_k(const float* __restrict__ Wq, const float* __restrict__ Wk,
                                              const float* __restrict__ Wv, const float* __restrict__ Wo,
                                              unsigned short* __restrict__ Wbf){
  const int bid = blockIdx.x;                       // 4096 blocks
  const int which = bid >> 10;
  const float* src = (which==0) ? Wq : (which==1) ? Wk : (which==2) ? Wv : Wo;
  unsigned short* dst = Wbf + ((size_t)which << 20);
  const int i = (bid & 1023)*256 + threadIdx.x;
  float4 v = ((const float4*)src)[i];
  ushort4 o;
  o.x = f2bf(v.x); o.y = f2bf(v.y); o.z = f2bf(v.z); o.w = f2bf(v.w);
  ((ushort4*)dst)[i] = o;
}

// ---------------- QKV GEMM: 128x128, A staged as f32 with XOR-swizzle (R9 post-mortem:
// f32 128B rows = 16-way bank conflict, 11M cycles; fix = pre-swizzled source + XOR read,
// rule 21 both-sides). B (bf16, 64B rows) swizzled 8-way -> 4-way. XCD-chunked remap. ----
__global__ __launch_bounds__(256) void gemm_qkv(const float* __restrict__ Qf, const float* __restrict__ Kf,
                                                const float* __restrict__ Vf, const short* __restrict__ Wbf,
                                                unsigned short* __restrict__ qh, unsigned short* __restrict__ kh,
                                                unsigned short* __restrict__ vT){
  __shared__ float lsA[2][4096];   // [buf][128 rows x 32 k] f32, XOR-swizzled sw=(row&7)<<4
  __shared__ short lsB[2][4096];   // [buf][128 rows x 32 k] bf16, XOR-swizzled sw=(row&3)<<4
  const int tid = threadIdx.x;
  const int hw = blockIdx.x;                         // 768 blocks
  const int logical = (hw & 7)*96 + (hw >> 3);       // bijective (768 = 8*96)
  const int z = logical >> 8, rem = logical & 255;
  const int my = rem >> 3, nx = rem & 7;
  const float* A = (z==0) ? Qf : (z==1) ? Kf : Vf;
  const short* W = Wbf + (size_t)z*ND*ND;
  unsigned short* out = (z==0) ? qh : (z==1) ? kh : vT;
  const int mode = (z==2) ? 1 : 0;
  const int m0 = my*128, n0 = nx*128;

  const float* gA = A + (size_t)m0*1024;
  const short* gB = W + (size_t)n0*1024;
  // A staging: 8 threads/row x 16B, 4 passes; source col pre-swizzled by (row&7)<<4
  const int arow = tid>>3;                                  // row within pass (0..31)
  const int acol = (((tid&7)*16) ^ ((arow&7)<<4)) >> 2;     // float idx within 128B row
  // B staging: 4 threads/row x 16B, 2 passes; source col pre-swizzled by (row&3)<<4
  const int brow = tid>>2;                                  // row within pass (0..63)
  const int bcol = (((tid&3)*16) ^ ((brow&3)<<4)) >> 1;     // short idx within 64B row
  const int w = tid>>6, lane = tid&63, lr = lane&15, lk = lane>>4;
  const int wm = w>>1, wn = w&1;

  f32x4 acc[4][4];
  #pragma unroll
  for (int i=0;i<4;++i)
    #pragma unroll
    for (int j=0;j<4;++j) acc[i][j] = (f32x4){0.f,0.f,0.f,0.f};

  // prologue: stage k-step 0 into buf 0 (dest linear: byte = pass*4096 + tid*16)
  #pragma unroll
  for (int r=0;r<4;++r)
    gload_lds16(gA + (size_t)(r*32+arow)*1024 + acol, &lsA[0][r*1024 + tid*4]);
  #pragma unroll
  for (int r=0;r<2;++r)
    gload_lds16(gB + (size_t)(r*64+brow)*1024 + bcol, &lsB[0][r*2048 + tid*8]);

  int cur = 0;
  for (int ks=0; ks<32; ++ks){
    __syncthreads();
    if (ks+1 < 32){
      const int k0 = (ks+1)*32;
      #pragma unroll
      for (int r=0;r<4;++r)
        gload_lds16(gA + (size_t)(r*32+arow)*1024 + k0 + acol, &lsA[cur^1][r*1024 + tid*4]);
      #pragma unroll
      for (int r=0;r<2;++r)
        gload_lds16(gB + (size_t)(r*64+brow)*1024 + k0 + bcol, &lsB[cur^1][r*2048 + tid*8]);
    }
    bf16x8 af[4], bfr[4];
    #pragma unroll
    for (int i=0;i<4;++i){
      const int ra = wm*64 + i*16 + lr;                 // A row
      const int swa = (ra&7)<<4;
      const char* abase = (const char*)&lsA[cur][0] + ra*128;
      const float4 lo = *(const float4*)(abase + ((lk*32)      ^ swa));
      const float4 hi = *(const float4*)(abase + ((lk*32 + 16) ^ swa));
      u32x4 aw = { cvtpk_bf16(lo.x, lo.y), cvtpk_bf16(lo.z, lo.w),
                   cvtpk_bf16(hi.x, hi.y), cvtpk_bf16(hi.z, hi.w) };
      af[i] = __builtin_bit_cast(bf16x8, aw);
      const int rb = wn*64 + i*16 + lr;                 // B row
      const char* bbase = (const char*)&lsB[cur][0] + rb*64;
      bfr[i] = *(const bf16x8*)(bbase + ((lk*16) ^ ((rb&3)<<4)));
    }
    #pragma unroll
    for (int i=0;i<4;++i)
      #pragma unroll
      for (int j=0;j<4;++j)
        acc[i][j] = __builtin_amdgcn_mfma_f32_16x16x32_bf16(af[i], bfr[j], acc[i][j], 0,0,0);
    cur ^= 1;
  }
  // epilogue: C/D layout col=lane&15, row=(lane>>4)*4+r
  #pragma unroll
  for (int i=0;i<4;++i)
    #pragma unroll
    for (int j=0;j<4;++j)
      #pragma unroll
      for (int r=0;r<4;++r){
        const int m = m0 + wm*64 + i*16 + lk*4 + r;
        const int n = n0 + wn*64 + j*16 + lr;
        const float v = acc[i][j][r];
        const int b = m>>11, s = m&2047, h = n>>6, dk = n&63;
        size_t addr;
        if (mode == 0) addr = (((size_t)(b*NH+h))*NS + s)*NDK + dk;     // [b,h,s,dk]
        else           addr = (((size_t)(b*NH+h))*NDK + dk)*NS + s;     // [b,h,dk,s]
        out[addr] = f2bf(v);
      }
}

// ---------------- output projection: 128x128 m97 core + fused residual ----------------
__global__ __launch_bounds__(256) void gemm_out(const short* __restrict__ Attn, const short* __restrict__ Wo,
                                                const float* __restrict__ Qin, float* __restrict__ proj){
  __shared__ short lsA[2][4096];
  __shared__ short lsB[2][4096];
  const int tid = threadIdx.x;
  const int hw = blockIdx.x;                        // 256 blocks
  const int logical = (hw & 7)*32 + (hw >> 3);      // bijective (256 = 8*32)
  const int my = logical >> 3, nx = logical & 7;
  const int m0 = my*128, n0 = nx*128;
  const short* gA = Attn + (size_t)m0*1024;
  const short* gB = Wo + (size_t)n0*1024;
  const int srow = tid>>2, scol = (tid&3)*8;
  const int w = tid>>6, lane = tid&63, lr = lane&15, lk = lane>>4;
  const int wm = w>>1, wn = w&1;

  f32x4 acc[4][4];
  #pragma unroll
  for (int i=0;i<4;++i)
    #pragma unroll
    for (int j=0;j<4;++j) acc[i][j] = (f32x4){0.f,0.f,0.f,0.f};

  #pragma unroll
  for (int r=0;r<2;++r){
    gload_lds16(gA + (size_t)(r*64+srow)*1024 + scol, &lsA[0][(r*256+tid)*8]);
    gload_lds16(gB + (size_t)(r*64+srow)*1024 + scol, &lsB[0][(r*256+tid)*8]);
  }
  int cur = 0;
  for (int ks=0; ks<32; ++ks){
    __syncthreads();
    if (ks+1 < 32){
      const int k0 = (ks+1)*32;
      #pragma unroll
      for (int r=0;r<2;++r){
        gload_lds16(gA + (size_t)(r*64+srow)*1024 + k0 + scol, &lsA[cur^1][(r*256+tid)*8]);
        gload_lds16(gB + (size_t)(r*64+srow)*1024 + k0 + scol, &lsB[cur^1][(r*256+tid)*8]);
      }
    }
    bf16x8 af[4], bfr[4];
    #pragma unroll
    for (int i=0;i<4;++i){
      af[i]  = *(const bf16x8*)&lsA[cur][(wm*64+i*16+lr)*32 + lk*8];
      bfr[i] = *(const bf16x8*)&lsB[cur][(wn*64+i*16+lr)*32 + lk*8];
    }
    #pragma unroll
    for (int i=0;i<4;++i)
      #pragma unroll
      for (int j=0;j<4;++j)
        acc[i][j] = __builtin_amdgcn_mfma_f32_16x16x32_bf16(af[i], bfr[j], acc[i][j], 0,0,0);
    cur ^= 1;
  }
  #pragma unroll
  for (int i=0;i<4;++i)
    #pragma unroll
    for (int j=0;j<4;++j)
      #pragma unroll
      for (int r=0;r<4;++r){
        const int m = m0 + wm*64 + i*16 + lk*4 + r;
        const int n = n0 + wn*64 + j*16 + lr;
        proj[(size_t)m*1024 + n] = acc[i][j][r] + Qin[(size_t)m*1024 + n];   // fused residual
      }
}

// ---------------- flash attention: LDS-staged K/V + in-block 2-way kv-split ----------------
// Grid: 512 blocks (XCD-chunked), 512 threads, LDS exactly 64KB -> 2 blocks/CU.
__global__ __launch_bounds__(512) void attn_k(const short* __restrict__ qh, const short* __restrict__ kh,
                                              const short* __restrict__ vT, const int* __restrict__ mask,
                                              unsigned short* __restrict__ attn){
  // LDS map: K [0,32K): half*8192 + buf*16384 ; V [32K,64K): +32768
  __shared__ char sb[65536];
  const int hw = blockIdx.x;                         // 512 blocks
  const int logical = (hw & 7)*64 + (hw >> 3);       // bijective (512 = 8*64)
  const int qb = logical & 15, h = (logical>>4)&15, b = logical>>8;
  const int tid = threadIdx.x, w = tid>>6, lane = tid&63;
  const int ql = lane & 31, hi = lane>>5;
  const int qw = w & 3, half = w>>2;
  const int bh = b*NH + h;
  const int q0 = qb*128 + qw*32;
  const float C2 = 0.18033688f;   // 0.125 * log2(e)

  // staging addressing: D = linear dest byte in 8KB tile; S = pre-swizzled source byte
  const int D = tid*16;                          // 512 threads x 16B = 8KB tile
  const int strow = D>>7;                        // tile row (kv for K, dk for V)
  const int S = D ^ ((strow&7)<<4);
  const char* ksrc = (const char*)(kh + (size_t)bh*NS*NDK) + S;                    // + kv*128
  const char* vsrc = (const char*)(vT + ((size_t)bh*NDK + strow)*NS) + (S & 127);  // + kv*2

  // Q as B-fragments: lane holds Q[q0+ql][kp*16 + hi*8 + j]
  const short* qrow = qh + ((size_t)bh*NS + q0 + ql)*NDK + hi*8;
  bf16x8 qf[4];
  #pragma unroll
  for (int kp=0;kp<4;++kp) qf[kp] = *(const bf16x8*)(qrow + kp*16);

  const int* mrow = mask + b*NS + half*1024;

  // prologue: stage tile 0 of both halves into buf 0
  gload_lds16(ksrc,                      sb + D);
  gload_lds16(ksrc + (size_t)1024*128,   sb + 8192 + D);
  gload_lds16(vsrc,                      sb + 32768 + D);
  gload_lds16(vsrc + (size_t)1024*2,     sb + 32768 + 8192 + D);

  f32x16 o0, o1;
  #pragma unroll
  for (int r=0;r<16;++r){ o0[r]=0.f; o1[r]=0.f; }
  float mrun = -1e30f, lrun = 0.f;

  const int swz = (ql&7)<<4;

  for (int t=0; t<16; ++t){
    const int buf = (t&1)*16384;
    __syncthreads();                              // staged loads for buf[t&1] arrived
    if (t+1 < 16){
      const int nbuf = ((t+1)&1)*16384;
      const size_t kvn0 = (size_t)(t+1)*64, kvn1 = 1024 + kvn0;
      gload_lds16(ksrc + kvn0*128, sb + nbuf + D);
      gload_lds16(ksrc + kvn1*128, sb + nbuf + 8192 + D);
      gload_lds16(vsrc + kvn0*2,   sb + 32768 + nbuf + D);
      gload_lds16(vsrc + kvn1*2,   sb + 32768 + nbuf + 8192 + D);
    }
    const unsigned long long bal = __ballot(mrow[t*64 + lane] != 0);
    const unsigned mw0 = (unsigned)bal, mw1 = (unsigned)(bal>>32);
    const bool allm = (~bal) == 0ull;

    const char* kb = sb + buf + half*8192;
    const char* vb = sb + 32768 + buf + half*8192;

    bf16x8 kf[8];
    #pragma unroll
    for (int kvh=0;kvh<2;++kvh)
      #pragma unroll
      for (int kp=0;kp<4;++kp)
        kf[kvh*4+kp] = *(const bf16x8*)(kb + (((kvh*32+ql)*128 + kp*32 + hi*16) ^ swz));

    f32x16 s0, s1;
    #pragma unroll
    for (int r=0;r<16;++r){ s0[r]=0.f; s1[r]=0.f; }
    __builtin_amdgcn_s_setprio(1);
    #pragma unroll
    for (int kp=0;kp<4;++kp){
      s0 = mfma32(kf[kp],   qf[kp], s0);
      s1 = mfma32(kf[4+kp], qf[kp], s1);
    }
    __builtin_amdgcn_s_setprio(0);

    float t16[16];
    #pragma unroll
    for (int r=0;r<16;++r) t16[r] = fmaxf(s0[r], s1[r]);
    #pragma unroll
    for (int st=8; st>=1; st>>=1)
      #pragma unroll
      for (int r=0;r<st;++r) t16[r] = fmaxf(t16[r], t16[r+st]);
    const float tm = fmaxf(t16[0], __shfl_xor(t16[0], 32, 64));

    // T13 defer-max
    if (!__all(tm - mrun <= 32.f)){
      const float mnew = fmaxf(mrun, tm);
      const float fac  = fexp2((mrun - mnew)*C2);
      mrun = mnew;
      #pragma unroll
      for (int r=0;r<16;++r){ o0[r]*=fac; o1[r]*=fac; }
      lrun *= fac;
    }
    const float nb = mrun*C2;

    bf16x8 vf[8];
    #pragma unroll
    for (int dh=0;dh<2;++dh)
      #pragma unroll
      for (int c=0;c<4;++c)
        vf[dh*4+c] = *(const bf16x8*)(vb + (((dh*32+ql)*128 + c*32 + hi*16) ^ swz));

    float psum = 0.f;
    #pragma unroll
    for (int kvh=0; kvh<2; ++kvh){
      const f32x16& ss = kvh ? s1 : s0;
      const unsigned mw = kvh ? mw1 : mw0;
      unsigned pwd[8];
      float ps0 = 0.f, ps1 = 0.f;
      #pragma unroll
      for (int i=0;i<8;++i){
        const int bp0 = ((2*i)&3) + 8*((2*i)>>2);   // {0,2,8,10,16,18,24,26}
        float p0 = fexp2(ss[2*i]*C2   - nb);
        float p1 = fexp2(ss[2*i+1]*C2 - nb);
        if (!allm){
          p0 = ((mw >> (bp0     + 4*hi)) & 1u) ? p0 : 0.f;
          p1 = ((mw >> (bp0 + 1 + 4*hi)) & 1u) ? p1 : 0.f;
        }
        ps0 += p0; ps1 += p1;
        pwd[i] = cvtpk_bf16(p0, p1);
      }
      psum += ps0 + ps1;
      swap32(pwd[0], pwd[2]);
      swap32(pwd[1], pwd[3]);
      swap32(pwd[4], pwd[6]);
      swap32(pwd[5], pwd[7]);
      u32x4 c0w = {pwd[0], pwd[1], pwd[2], pwd[3]};
      u32x4 c1w = {pwd[4], pwd[5], pwd[6], pwd[7]};
      bf16x8 pf0 = __builtin_bit_cast(bf16x8, c0w);
      bf16x8 pf1 = __builtin_bit_cast(bf16x8, c1w);
      __builtin_amdgcn_s_setprio(1);
      o0 = mfma32(vf[2*kvh],       pf0, o0);
      o1 = mfma32(vf[4 + 2*kvh],   pf0, o1);
      o0 = mfma32(vf[2*kvh + 1],   pf1, o0);
      o1 = mfma32(vf[4 + 2*kvh+1], pf1, o1);
      __builtin_amdgcn_s_setprio(0);
    }
    psum += __shfl_xor(psum, 32, 64);
    lrun += psum;
  }

  // ---- combine the two kv halves (pairs w <-> w+4 share q rows) ----
  __syncthreads();                                // all staging reads done; LDS reusable
  float* smm = (float*)(sb + 32768);              // [8][32]
  float* sml = (float*)(sb + 32768 + 1024);
  if (hi == 0){ smm[w*32 + ql] = mrun; sml[w*32 + ql] = lrun; }
  __syncthreads();
  const float pmv = smm[(w^4)*32 + ql], plv = sml[(w^4)*32 + ql];
  const float mfin = fmaxf(mrun, pmv);
  const float facS = fexp2((mrun - mfin)*C2);
  if (w >= 4){
    float* eg = (float*)(sb + (size_t)(w-4)*8192);
    #pragma unroll
    for (int r=0;r<16;++r){
      eg[ql + 32*(hi*16 + r)]        = o0[r]*facS;
      eg[ql + 32*(hi*16 + r) + 1024] = o1[r]*facS;
    }
  }
  __syncthreads();
  if (w < 4){
    float* eg = (float*)(sb + (size_t)w*8192);
    #pragma unroll
    for (int r=0;r<16;++r){
      o0[r] = o0[r]*facS + eg[ql + 32*(hi*16 + r)];
      o1[r] = o1[r]*facS + eg[ql + 32*(hi*16 + r) + 1024];
    }
    const float facP = fexp2((pmv - mfin)*C2);
    const float lfin = lrun*facS + plv*facP;
    const float inv = 1.f / lfin;
    asm volatile("s_waitcnt lgkmcnt(0)" ::: "memory");   // reads done before overwrite
    char* ep = sb + (size_t)w*8192;
    #pragma unroll
    for (int dh=0; dh<2; ++dh){
      const f32x16& oo = dh ? o1 : o0;
      #pragma unroll
      for (int i=0;i<8;++i){
        const int d0 = ((2*i)&3) + 8*((2*i)>>2) + 4*hi + dh*32;
        const unsigned pk = cvtpk_bf16(oo[2*i]*inv, oo[2*i+1]*inv);
        *(unsigned*)(ep + (((ql*128) + d0*2) ^ ((ql&7)<<4))) = pk;
      }
    }
    asm volatile("s_waitcnt lgkmcnt(0)" ::: "memory");
    #pragma unroll
    for (int seg=0; seg<4; ++seg){
      const int qq = seg*8 + (lane>>3), dc = (lane&7)*8;
      bf16x8 vv = *(const bf16x8*)(ep + (((qq*128) + dc*2) ^ ((qq&7)<<4)));
      *(bf16x8*)(attn + ((size_t)b*NS + q0 + qq)*ND + h*NDK + dc) = vv;
    }
  }
}

// ---------------- LayerNorm (1 wave per row; residual already in proj) ----------------
__global__ __launch_bounds__(256) void ln_k(const float* __restrict__ proj,
                                            const float* __restrict__ gamma, const float* __restrict__ beta,
                                            float* __restrict__ out){
  const int row = blockIdx.x*4 + (threadIdx.x>>6);
  const int lane = threadIdx.x & 63;
  const float4* pp = (const float4*)(proj + (size_t)row*ND);
  float4 x[4];
  float sum = 0.f;
  #pragma unroll
  for (int i=0;i<4;++i){
    x[i] = pp[lane + i*64];
    sum += x[i].x + x[i].y + x[i].z + x[i].w;
  }
  #pragma unroll
  for (int off=32; off>=1; off>>=1) sum += __shfl_xor(sum, off, 64);
  const float mu = sum * (1.f/1024.f);
  float vs = 0.f;
  #pragma unroll
  for (int i=0;i<4;++i){
    float d0=x[i].x-mu, d1=x[i].y-mu, d2=x[i].z-mu, d3=x[i].w-mu;
    vs += d0*d0 + d1*d1 + d2*d2 + d3*d3;
  }
  #pragma unroll
  for (int off=32; off>=1; off>>=1) vs += __shfl_xor(vs, off, 64);
  const float rstd = rsqrtf(vs*(1.f/1024.f) + 1e-5f);
  #pragma unroll
  for (int i=0;i<4;++i){
    const float4 g  = ((const float4*)gamma)[lane + i*64];
    const float4 be = ((const float4*)beta)[lane + i*64];
    float4 y;
    y.x = (x[i].x-mu)*rstd*g.x + be.x;
    y.y = (x[i].y-mu)*rstd*g.y + be.y;
    y.z = (x[i].z-mu)*rstd*g.z + be.z;
    y.w = (x[i].w-mu)*rstd*g.w + be.w;
    ((float4*)(out + (size_t)row*ND))[lane + i*64] = y;
  }
}

// ---------------- launch ----------------
// ws layout (64 MB):
//   [0,8MB)   Wbf: Wq,Wk,Wv,Wo bf16
//   [8,24MB)  proj f32 (written by gemm_out)
//   [32,40)   qh bf16 [b,h,s,dk]
//   [40,48)   kh bf16 [b,h,s,dk]
//   [48,56)   vT bf16 [b,h,dk,s]
//   [56,64)   attn bf16 [b,s,d]
extern "C" void kernel_launch(void* const* d_in, const int* in_sizes, int n_in,
                              void* d_out, int out_size, void* d_ws, size_t ws_size,
                              hipStream_t stream){
  const float* Q    = (const float*)d_in[0];
  const float* K    = (const float*)d_in[1];
  const float* V    = (const float*)d_in[2];
  const int*   mask = (const int*)  d_in[3];
  const float* Wq   = (const float*)d_in[4];
  const float* Wk   = (const float*)d_in[5];
  const float* Wv   = (const float*)d_in[6];
  const float* Wo   = (const float*)d_in[7];
  const float* gam  = (const float*)d_in[8];
  const float* bet  = (const float*)d_in[9];
  float* out = (float*)d_out;
  char* ws = (char*)d_ws;

  unsigned short* Wbf  = (unsigned short*)(ws);
  unsigned short* qhp  = (unsigned short*)(ws + (size_t)(32u<<20));
  unsigned short* khp  = (unsigned short*)(ws + (size_t)(40u<<20));
  unsigned short* vTp  = (unsigned short*)(ws + (size_t)(48u<<20));
  unsigned short* attb = (unsigned short*)(ws + (size_t)(56u<<20));
  float* proj  = (float*)(ws + (size_t)(8u<<20));

  prep_k<<<4096,256,0,stream>>>(Wq, Wk, Wv, Wo, Wbf);

  gemm_qkv<<<768,256,0,stream>>>(Q, K, V, (const short*)Wbf, qhp, khp, vTp);

  attn_k<<<512,512,0,stream>>>((const short*)qhp, (const short*)khp, (const short*)vTp, mask, attb);

  gemm_out<<<256,256,0,stream>>>((const short*)attb, (const short*)(Wbf + (3u<<20)), Q, proj);

  ln_k<<<1024,256,0,stream>>>(proj, gam, bet, out);
}